// Round 9
// baseline (2565.175 us; speedup 1.0000x reference)
//
#include <hip/hip_runtime.h>
#include <stdint.h>

// Problem constants (from reference): B=8, L=4096, D=1024, S=255
constexpr int kB = 8;
constexpr int kL = 4096;
constexpr int kD = 1024;
constexpr int kS = 255;
constexpr int kM = kB * kL;   // 32768 rows of A / out
constexpr int kK = 2 * kD;    // 2048 reduction dim
constexpr int kN = kD;        // 1024 output features

typedef __bf16 bf16x8 __attribute__((ext_vector_type(8)));
typedef float  f32x4  __attribute__((ext_vector_type(4)));

// ---- workspace layout (bytes): full bf16 mirror (R2 layout) ----
constexpr size_t WS_WORDS = 0;                                   // 67,108,864 B bf16
constexpr size_t WS_SENTS = WS_WORDS + (size_t)kM * kD * 2;
constexpr size_t WS_W     = WS_SENTS + (size_t)kB * kS * kD * 2; // +4,177,920
constexpr size_t WS_ZP    = WS_W + (size_t)kN * kK * 2;          // +4,194,304
constexpr size_t WS_NEED  = WS_ZP + 3072;                        // zero page 3 KiB

// fp32 pair -> packed bf16x2, round-half-up (validated R0-R8)
__device__ __forceinline__ uint32_t pk_bf16x2(float a, float b) {
    uint32_t ua = __float_as_uint(a) + 0x8000u;
    uint32_t ub = __float_as_uint(b) + 0x8000u;
    return __builtin_amdgcn_perm(ub, ua, 0x07060302u);
}

// async global->LDS 16B per lane: dest = wave-uniform base + lane*16
__device__ __forceinline__ void async16(const void* g, void* l) {
    __builtin_amdgcn_global_load_lds(
        (const __attribute__((address_space(1))) uint32_t*)g,
        (__attribute__((address_space(3))) uint32_t*)l, 16, 0, 0);
}

#define WAITVM(n)  asm volatile("s_waitcnt vmcnt(" #n ")" ::: "memory")
#define WAITLGKM0  asm volatile("s_waitcnt lgkmcnt(0)" ::: "memory")

__device__ __forceinline__ void blockbar() {
    __builtin_amdgcn_sched_barrier(0);
    __builtin_amdgcn_s_barrier();
    __builtin_amdgcn_sched_barrier(0);
}

// ===================== prepass (R2-proven): fp32 -> bf16, grid-stride =======
__global__ __launch_bounds__(256)
void cvt_prepass2(const float4* __restrict__ words, const float4* __restrict__ sents,
                  const float4* __restrict__ W,
                  uint4* __restrict__ wordsB, uint4* __restrict__ sentsB,
                  uint4* __restrict__ WB, uint32_t* __restrict__ zp)
{
    constexpr size_t NW8 = (size_t)kM * kD / 8;       // 4,194,304
    constexpr size_t NS8 = (size_t)kB * kS * kD / 8;  //   261,120
    constexpr size_t NB8 = (size_t)kN * kK / 8;       //   262,144
    constexpr size_t NT8 = NW8 + NS8 + NB8;
    if (blockIdx.x == 0) {                            // zero page for invalid rows
        for (int t = threadIdx.x; t < 768; t += 256) zp[t] = 0u;
    }
    const size_t stride = (size_t)gridDim.x * blockDim.x;
    for (size_t i = (size_t)blockIdx.x * blockDim.x + threadIdx.x; i < NT8; i += stride) {
        const float4* src; uint4* dst; size_t j;
        if (i < NW8)            { src = words; dst = wordsB; j = i; }
        else if (i < NW8 + NS8) { src = sents; dst = sentsB; j = i - NW8; }
        else                    { src = W;     dst = WB;     j = i - NW8 - NS8; }
        float4 a  = src[2 * j];
        float4 b2 = src[2 * j + 1];
        uint4 o;
        o.x = pk_bf16x2(a.x,  a.y);
        o.y = pk_bf16x2(a.z,  a.w);
        o.z = pk_bf16x2(b2.x, b2.y);
        o.w = pk_bf16x2(b2.z, b2.w);
        dst[j] = o;
    }
}

// ===================== GEMM v9: v7 kernel at 2 blocks/CU (TLP) ==============
// C[m,n] = relu( sum_k A[m,k]*W[n,k] + bias[n] )
// SINGLE VARIABLE vs v7: LDS 128KB->64KB (2 buffers) so TWO blocks co-reside
// per CU (4 waves/SIMD). grid 512 = exactly 2 blocks/CU, ONE round (v7 ran 2
// serial rounds at 1 block/CU). Cost: prefetch depth drops to 1 -> vmcnt
// drains to 0 each kstep (v6 showed -13% at 1 block/CU); bet: cross-block TLP
// covers the drain+barrier stalls (m97/m114 regime: drain-everything + multi-
// block = 874 TF). Frag-linear LDS (0 conflicts), setprio, XCD swizzle kept.
// Lifetime: stage(t+2) at phase B overwrites buf[t&1]; all reads of buf[t&1]
// (ag(t) phase A, af/bf(t) at t-1 phase B) drained at this kstep's WAITLGKM0
// before the mid barrier; stage is issued after that barrier.
__global__ __launch_bounds__(512, 4)
void wsib_gemm_v9(const uint8_t* __restrict__ wordsB,   // [32768][1024] bf16
                  const uint8_t* __restrict__ sentsB,   // [8*255][1024] bf16
                  const uint8_t* __restrict__ WB,       // [1024][2048]  bf16
                  const float*   __restrict__ bias,
                  const int*     __restrict__ smap,
                  const uint8_t* __restrict__ zp,
                  float* __restrict__ out)
{
    __shared__ uint8_t lds[2][2][16384];   // [buf][A=0/B=1][frag-linear 16KB]

    const int tid  = threadIdx.x;
    const int w    = tid >> 6;           // wave 0..7
    const int lane = tid & 63;

    // XCD-aware bijective swizzle (nwg=512, 512%8==0) — proven FETCH halver
    const int lin = blockIdx.y * gridDim.x + blockIdx.x;   // 0..511
    const int swz = (lin & 7) * 64 + (lin >> 3);
    const int nT = swz & 3;              // 0..3
    const int mT = swz >> 2;             // 0..127

    const int wm = (w >> 2) * 128;       // 0 or 128
    const int wn = (w & 3) * 64;         // 0,64,128,192
    const int fr = lane & 15, quad = lane >> 4;
    const int lo = lane * 16;            // frag-linear lane offset
    const int slabA = (w >> 2) * 8;      // wm/16
    const int slabB = (w & 3) * 4;       // wn/16

    float bv[4];
    #pragma unroll
    for (int ni = 0; ni < 4; ++ni) bv[ni] = bias[nT * 256 + wn + ni * 16 + fr];

    // ---- staging source pointers (frag-linear inverse mapping, as v7) ----
    const int colb = quad * 16;
    const int r0 = w * 16 + fr, r1 = r0 + 128;
    const int gA0 = mT * 256 + r0, gA1 = mT * 256 + r1;
    const int bIdx = gA0 >> 12;               // tile never crosses batch
    const uint8_t* aw0 = wordsB + (size_t)gA0 * 2048 + colb;
    const uint8_t* aw1 = wordsB + (size_t)gA1 * 2048 + colb;
    const int s0 = smap[gA0], s1 = smap[gA1];
    const uint8_t* as0 = (s0 >= 0) ? sentsB + (size_t)(bIdx * kS + s0) * 2048 + colb : zp + colb;
    const uint8_t* as1 = (s1 >= 0) ? sentsB + (size_t)(bIdx * kS + s1) * 2048 + colb : zp + colb;
    const uint8_t* pB0 = WB + (size_t)(nT * 256 + r0) * 4096 + colb;
    const uint8_t* pB1 = WB + (size_t)(nT * 256 + r1) * 4096 + colb;

    auto stage = [&](int buf, int t) {   // 4 loads: A j0,j1; B j0,j1
        uint8_t* A  = (uint8_t*)lds[buf][0];
        uint8_t* Bb = (uint8_t*)lds[buf][1];
        const uint8_t* a0 = (t < 32) ? aw0 + t * 64 : as0 + (t - 32) * 64;
        const uint8_t* a1 = (t < 32) ? aw1 + t * 64 : as1 + (t - 32) * 64;
        async16(a0, A + w * 1024);
        async16(a1, A + 8192 + w * 1024);
        async16(pB0 + t * 64, Bb + w * 1024);
        async16(pB1 + t * 64, Bb + 8192 + w * 1024);
    };

    f32x4 acc[8][4];
    #pragma unroll
    for (int i = 0; i < 8; ++i)
        #pragma unroll
        for (int j = 0; j < 4; ++j) acc[i][j] = (f32x4){0.f, 0.f, 0.f, 0.f};

    // ---- prologue: stage tiles 0,1; tile 0 complete; prime frags(0) ----
    stage(0, 0);
    stage(1, 1);
    WAITVM(4);
    blockbar();

    bf16x8 af[4], bfA[4], bfB[4];
    #pragma unroll
    for (int mi = 0; mi < 4; ++mi)
        af[mi] = *(const bf16x8*)((uint8_t*)lds[0][0] + (slabA + mi) * 1024 + lo);
    #pragma unroll
    for (int ni = 0; ni < 4; ++ni)
        bfA[ni] = *(const bf16x8*)((uint8_t*)lds[0][1] + (slabB + ni) * 1024 + lo);

    // ---- main loop: 64 K-steps of 32, 1 barrier each (v7 schedule, 2 bufs) ----
    auto kstep = [&](int t, bf16x8 (&bfc)[4], bf16x8 (&bfn)[4]) {
        uint8_t* bufT = (uint8_t*)lds[t & 1][0];

        // phase A: read ag(t) (slabs +4..+7), MFMA-A (acc rows 0..63)
        bf16x8 ag[4];
        #pragma unroll
        for (int mi = 0; mi < 4; ++mi)
            ag[mi] = *(const bf16x8*)(bufT + (slabA + 4 + mi) * 1024 + lo);
        __builtin_amdgcn_s_setprio(1);
        #pragma unroll
        for (int mi = 0; mi < 4; ++mi)
            #pragma unroll
            for (int ni = 0; ni < 4; ++ni)
                acc[mi][ni] = __builtin_amdgcn_mfma_f32_16x16x32_bf16(
                    af[mi], bfc[ni], acc[mi][ni], 0, 0, 0);
        __builtin_amdgcn_s_setprio(0);

        // mid: drain own ds_reads; tile t+1 DMA complete; publish via barrier
        WAITLGKM0;
        WAITVM(0);
        blockbar();

        // phase B: stage tile t+2 into buf[t&1], read frags(t+1), MFMA-B
        if (t + 2 < 64) stage(t & 1, t + 2);
        if (t + 1 < 64) {
            uint8_t* bufNA = (uint8_t*)lds[(t + 1) & 1][0];
            uint8_t* bufNB = (uint8_t*)lds[(t + 1) & 1][1];
            #pragma unroll
            for (int ni = 0; ni < 4; ++ni)
                bfn[ni] = *(const bf16x8*)(bufNB + (slabB + ni) * 1024 + lo);
            #pragma unroll
            for (int mi = 0; mi < 4; ++mi)
                af[mi] = *(const bf16x8*)(bufNA + (slabA + mi) * 1024 + lo);
        }
        __builtin_amdgcn_s_setprio(1);
        #pragma unroll
        for (int mi = 0; mi < 4; ++mi)
            #pragma unroll
            for (int ni = 0; ni < 4; ++ni)
                acc[mi + 4][ni] = __builtin_amdgcn_mfma_f32_16x16x32_bf16(
                    ag[mi], bfc[ni], acc[mi + 4][ni], 0, 0, 0);
        __builtin_amdgcn_s_setprio(0);
    };

    #pragma unroll 1
    for (int t2 = 0; t2 < 32; ++t2) {
        kstep(2 * t2,     bfA, bfB);
        kstep(2 * t2 + 1, bfB, bfA);
    }

    // ---- epilogue: bias + relu, fp32 store ----
    // C/D layout (verified): col = lane&15, row = quad*4 + r
    const int rowBase = mT * 256 + wm + quad * 4;
    const int colBase = nT * 256 + wn + fr;
    #pragma unroll
    for (int mi = 0; mi < 8; ++mi) {
        #pragma unroll
        for (int ni = 0; ni < 4; ++ni) {
            const int col = colBase + ni * 16;
            #pragma unroll
            for (int r = 0; r < 4; ++r) {
                const int row = rowBase + mi * 16 + r;
                out[(size_t)row * kN + col] = fmaxf(acc[mi][ni][r] + bv[ni], 0.f);
            }
        }
    }
}

// ===================== fallback (R2 kernel, no-workspace path) ==============
#define TILE_M 128
#define TILE_N 128
#define TILE_K 32
#define LDS_STRIDE 20
__global__ __launch_bounds__(256)
void wsib_gemm_fb(const float* __restrict__ words, const float* __restrict__ sents,
                  const float* __restrict__ W, const float* __restrict__ bias,
                  const int* __restrict__ smap, float* __restrict__ out)
{
    __shared__ uint32_t Asm[TILE_M * LDS_STRIDE];
    __shared__ uint32_t Bsm[TILE_N * LDS_STRIDE];
    const int tid = threadIdx.x, nT = blockIdx.x, mT = blockIdx.y;
    const int sRow = tid >> 1, half = tid & 1;
    const int mRow = mT * TILE_M + sRow, bIdx = mRow >> 12;
    const float* wsrc = words + (size_t)mRow * kD + half * 16;
    const int sidx = smap[mRow];
    const float* ssrc = (sidx >= 0) ? sents + ((size_t)bIdx * kS + sidx) * kD + half * 16 : nullptr;
    const float* bsrc = W + (size_t)(nT * TILE_N + sRow) * kK + half * 16;
    uint32_t* adst = &Asm[sRow * LDS_STRIDE + half * 8];
    uint32_t* bdst = &Bsm[sRow * LDS_STRIDE + half * 8];
    const int lane = tid & 63, wv = tid >> 6;
    const int wm = (wv & 1) * 64, wn = (wv >> 1) * 64;
    const int fr = lane & 15, quad = lane >> 4;
    f32x4 acc[4][4];
    #pragma unroll
    for (int i = 0; i < 4; ++i)
        #pragma unroll
        for (int j = 0; j < 4; ++j) acc[i][j] = (f32x4){0.f, 0.f, 0.f, 0.f};
    float4 ra[4], rb[4];
    {
        const float4* pa = (const float4*)wsrc; const float4* pb = (const float4*)bsrc;
        #pragma unroll
        for (int i = 0; i < 4; ++i) { ra[i] = pa[i]; rb[i] = pb[i]; }
    }
    for (int k0 = 0; k0 < kK; k0 += TILE_K) {
        uint32_t pa[8], pb[8];
        #pragma unroll
        for (int i = 0; i < 4; ++i) {
            pa[2*i] = pk_bf16x2(ra[i].x, ra[i].y); pa[2*i+1] = pk_bf16x2(ra[i].z, ra[i].w);
            pb[2*i] = pk_bf16x2(rb[i].x, rb[i].y); pb[2*i+1] = pk_bf16x2(rb[i].z, rb[i].w);
        }
        __syncthreads();
        ((uint4*)adst)[0] = make_uint4(pa[0], pa[1], pa[2], pa[3]);
        ((uint4*)adst)[1] = make_uint4(pa[4], pa[5], pa[6], pa[7]);
        ((uint4*)bdst)[0] = make_uint4(pb[0], pb[1], pb[2], pb[3]);
        ((uint4*)bdst)[1] = make_uint4(pb[4], pb[5], pb[6], pb[7]);
        __syncthreads();
        const int k1 = k0 + TILE_K;
        if (k1 < kK) {
            const float* asrc = (k1 < kD) ? (wsrc + k1) : (ssrc ? (ssrc + (k1 - kD)) : nullptr);
            if (asrc) { const float4* p = (const float4*)asrc;
                #pragma unroll
                for (int i = 0; i < 4; ++i) ra[i] = p[i];
            } else {
                #pragma unroll
                for (int i = 0; i < 4; ++i) ra[i] = make_float4(0.f, 0.f, 0.f, 0.f);
            }
            const float4* p = (const float4*)(bsrc + k1);
            #pragma unroll
            for (int i = 0; i < 4; ++i) rb[i] = p[i];
        }
        bf16x8 af[4], bfv[4];
        #pragma unroll
        for (int mi = 0; mi < 4; ++mi)
            af[mi] = *(const bf16x8*)&Asm[(wm + mi * 16 + fr) * LDS_STRIDE + quad * 4];
        #pragma unroll
        for (int ni = 0; ni < 4; ++ni)
            bfv[ni] = *(const bf16x8*)&Bsm[(wn + ni * 16 + fr) * LDS_STRIDE + quad * 4];
        #pragma unroll
        for (int mi = 0; mi < 4; ++mi)
            #pragma unroll
            for (int ni = 0; ni < 4; ++ni)
                acc[mi][ni] = __builtin_amdgcn_mfma_f32_16x16x32_bf16(af[mi], bfv[ni], acc[mi][ni], 0, 0, 0);
    }
    const int rowBase = mT * TILE_M + wm, colBase = nT * TILE_N + wn;
    float bv[4];
    #pragma unroll
    for (int ni = 0; ni < 4; ++ni) bv[ni] = bias[colBase + ni * 16 + fr];
    #pragma unroll
    for (int mi = 0; mi < 4; ++mi)
        #pragma unroll
        for (int ni = 0; ni < 4; ++ni) {
            const int col = colBase + ni * 16 + fr;
            #pragma unroll
            for (int r = 0; r < 4; ++r) {
                const int row = rowBase + mi * 16 + quad * 4 + r;
                out[(size_t)row * kN + col] = fmaxf(acc[mi][ni][r] + bv[ni], 0.f);
            }
        }
}

extern "C" void kernel_launch(void* const* d_in, const int* in_sizes, int n_in,
                              void* d_out, int out_size, void* d_ws, size_t ws_size,
                              hipStream_t stream) {
    const float* words = (const float*)d_in[0];   // [8, 4096, 1024] f32
    const float* sents = (const float*)d_in[1];   // [8, 255, 1024]  f32
    const float* W     = (const float*)d_in[2];   // [1024, 2048]    f32
    const float* bias  = (const float*)d_in[3];   // [1024]          f32
    const int*   smap  = (const int*)d_in[4];     // [8, 4096]       i32
    float* out = (float*)d_out;                   // [8, 4096, 1024] f32

    if (ws_size >= WS_NEED) {
        uint8_t* ws = (uint8_t*)d_ws;
        uint4* wordsB = (uint4*)(ws + WS_WORDS);
        uint4* sentsB = (uint4*)(ws + WS_SENTS);
        uint4* WB     = (uint4*)(ws + WS_W);
        uint32_t* zp  = (uint32_t*)(ws + WS_ZP);
        cvt_prepass2<<<2048, 256, 0, stream>>>(
            (const float4*)words, (const float4*)sents, (const float4*)W,
            wordsB, sentsB, WB, zp);
        dim3 grid(kN / 256, kM / 256);            // (4, 128)
        wsib_gemm_v9<<<grid, 512, 0, stream>>>(
            (const uint8_t*)wordsB, (const uint8_t*)sentsB, (const uint8_t*)WB,
            bias, smap, (const uint8_t*)zp, out);
    } else {
        dim3 grid(kN / TILE_N, kM / TILE_M);
        wsib_gemm_fb<<<grid, 256, 0, stream>>>(words, sents, W, bias, smap, out);
    }
}

// Round 11
// 370.024 us; speedup vs baseline: 6.9324x; 6.9324x over previous
//
#include <hip/hip_runtime.h>
#include <stdint.h>

// Problem constants (from reference): B=8, L=4096, D=1024, S=255
constexpr int kB = 8;
constexpr int kL = 4096;
constexpr int kD = 1024;
constexpr int kS = 255;
constexpr int kM = kB * kL;   // 32768 rows of A / out
constexpr int kK = 2 * kD;    // 2048 reduction dim
constexpr int kN = kD;        // 1024 output features

typedef __bf16 bf16x8 __attribute__((ext_vector_type(8)));
typedef float  f32x4  __attribute__((ext_vector_type(4)));

// ---- workspace layout (bytes): full bf16 mirror (R2 layout) ----
constexpr size_t WS_WORDS = 0;                                   // 67,108,864 B bf16
constexpr size_t WS_SENTS = WS_WORDS + (size_t)kM * kD * 2;
constexpr size_t WS_W     = WS_SENTS + (size_t)kB * kS * kD * 2; // +4,177,920
constexpr size_t WS_ZP    = WS_W + (size_t)kN * kK * 2;          // +4,194,304
constexpr size_t WS_NEED  = WS_ZP + 3072;                        // zero page 3 KiB

// fp32 pair -> packed bf16x2, round-half-up (validated R0-R9)
__device__ __forceinline__ uint32_t pk_bf16x2(float a, float b) {
    uint32_t ua = __float_as_uint(a) + 0x8000u;
    uint32_t ub = __float_as_uint(b) + 0x8000u;
    return __builtin_amdgcn_perm(ub, ua, 0x07060302u);
}

// async global->LDS 16B per lane: dest = wave-uniform base + lane*16
__device__ __forceinline__ void async16(const void* g, void* l) {
    __builtin_amdgcn_global_load_lds(
        (const __attribute__((address_space(1))) uint32_t*)g,
        (__attribute__((address_space(3))) uint32_t*)l, 16, 0, 0);
}

#define WAITVM(n)  asm volatile("s_waitcnt vmcnt(" #n ")" ::: "memory")
#define WAITLGKM0  asm volatile("s_waitcnt lgkmcnt(0)" ::: "memory")

__device__ __forceinline__ void blockbar() {
    __builtin_amdgcn_sched_barrier(0);
    __builtin_amdgcn_s_barrier();
    __builtin_amdgcn_sched_barrier(0);
}

// ============ prepass v3: fp32 -> bf16, 64B-read/32B-write per iter =========
// Region boundaries (in 16B-output units) are all even, so a thread's pair
// (j, j+1) never straddles two source arrays.
__global__ __launch_bounds__(256)
void cvt_prepass3(const float4* __restrict__ words, const float4* __restrict__ sents,
                  const float4* __restrict__ W,
                  uint4* __restrict__ wordsB, uint4* __restrict__ sentsB,
                  uint4* __restrict__ WB, uint32_t* __restrict__ zp)
{
    constexpr size_t NW8 = (size_t)kM * kD / 8;       // 4,194,304 (even)
    constexpr size_t NS8 = (size_t)kB * kS * kD / 8;  //   261,120 (even)
    constexpr size_t NB8 = (size_t)kN * kK / 8;       //   262,144 (even)
    constexpr size_t NPAIR = (NW8 + NS8 + NB8) / 2;   // 2,358,784
    if (blockIdx.x == 0) {                            // zero page for invalid rows
        for (int t = threadIdx.x; t < 768; t += 256) zp[t] = 0u;
    }
    const size_t stride = (size_t)gridDim.x * blockDim.x;
    for (size_t p = (size_t)blockIdx.x * blockDim.x + threadIdx.x; p < NPAIR; p += stride) {
        const size_t j = 2 * p;
        const float4* src; uint4* dst; size_t k;
        if (j < NW8)            { src = words; dst = wordsB; k = j; }
        else if (j < NW8 + NS8) { src = sents; dst = sentsB; k = j - NW8; }
        else                    { src = W;     dst = WB;     k = j - NW8 - NS8; }
        const float4 a0 = src[2 * k];
        const float4 a1 = src[2 * k + 1];
        const float4 a2 = src[2 * k + 2];
        const float4 a3 = src[2 * k + 3];
        uint4 o0, o1;
        o0.x = pk_bf16x2(a0.x, a0.y);  o0.y = pk_bf16x2(a0.z, a0.w);
        o0.z = pk_bf16x2(a1.x, a1.y);  o0.w = pk_bf16x2(a1.z, a1.w);
        o1.x = pk_bf16x2(a2.x, a2.y);  o1.y = pk_bf16x2(a2.z, a2.w);
        o1.z = pk_bf16x2(a3.x, a3.y);  o1.w = pk_bf16x2(a3.z, a3.w);
        dst[k]     = o0;
        dst[k + 1] = o1;
    }
}

// ===================== GEMM v7 (session best, verbatim from R7) =============
// C[m,n] = relu( sum_k A[m,k]*W[n,k] + bias[n] )
// T2+T4 conjunction: counted-vmcnt 1-barrier schedule + frag-linear LDS
// (0 bank conflicts). 150.5 us / ~910 TF / MfmaUtil 39% — verified structural
// plateau of the 256x256 1-block/CU tile (R9 proved 2 blocks/CU is VGPR-
// impossible for this tile: 16 waves x ~240 regs > unified RF -> acc spill).
__global__ __launch_bounds__(512, 2)
void wsib_gemm_v7(const uint8_t* __restrict__ wordsB,   // [32768][1024] bf16
                  const uint8_t* __restrict__ sentsB,   // [8*255][1024] bf16
                  const uint8_t* __restrict__ WB,       // [1024][2048]  bf16
                  const float*   __restrict__ bias,
                  const int*     __restrict__ smap,
                  const uint8_t* __restrict__ zp,
                  float* __restrict__ out)
{
    __shared__ uint8_t lds[4][2][16384];   // [buf][A=0/B=1][frag-linear 16KB]

    const int tid  = threadIdx.x;
    const int w    = tid >> 6;           // wave 0..7
    const int lane = tid & 63;
    const int nT = blockIdx.x;           // 0..3
    const int mT = blockIdx.y;           // 0..127

    const int wm = (w >> 2) * 128;       // 0 or 128
    const int wn = (w & 3) * 64;         // 0,64,128,192
    const int fr = lane & 15, quad = lane >> 4;
    const int lo = lane * 16;            // frag-linear lane offset
    const int slabA = (w >> 2) * 8;      // wm/16
    const int slabB = (w & 3) * 4;       // wn/16

    float bv[4];
    #pragma unroll
    for (int ni = 0; ni < 4; ++ni) bv[ni] = bias[nT * 256 + wn + ni * 16 + fr];

    // ---- staging source pointers (frag-linear inverse mapping) ----
    const int colb = quad * 16;
    const int r0 = w * 16 + fr, r1 = r0 + 128;
    const int gA0 = mT * 256 + r0, gA1 = mT * 256 + r1;
    const int bIdx = gA0 >> 12;               // tile never crosses batch
    const uint8_t* aw0 = wordsB + (size_t)gA0 * 2048 + colb;
    const uint8_t* aw1 = wordsB + (size_t)gA1 * 2048 + colb;
    const int s0 = smap[gA0], s1 = smap[gA1];
    const uint8_t* as0 = (s0 >= 0) ? sentsB + (size_t)(bIdx * kS + s0) * 2048 + colb : zp + colb;
    const uint8_t* as1 = (s1 >= 0) ? sentsB + (size_t)(bIdx * kS + s1) * 2048 + colb : zp + colb;
    const uint8_t* pB0 = WB + (size_t)(nT * 256 + r0) * 4096 + colb;
    const uint8_t* pB1 = WB + (size_t)(nT * 256 + r1) * 4096 + colb;

    auto stage = [&](int buf, int t) {   // 4 loads: A j0,j1; B j0,j1
        uint8_t* A  = (uint8_t*)lds[buf][0];
        uint8_t* Bb = (uint8_t*)lds[buf][1];
        const uint8_t* a0 = (t < 32) ? aw0 + t * 64 : as0 + (t - 32) * 64;
        const uint8_t* a1 = (t < 32) ? aw1 + t * 64 : as1 + (t - 32) * 64;
        async16(a0, A + w * 1024);
        async16(a1, A + 8192 + w * 1024);
        async16(pB0 + t * 64, Bb + w * 1024);
        async16(pB1 + t * 64, Bb + 8192 + w * 1024);
    };

    f32x4 acc[8][4];
    #pragma unroll
    for (int i = 0; i < 8; ++i)
        #pragma unroll
        for (int j = 0; j < 4; ++j) acc[i][j] = (f32x4){0.f, 0.f, 0.f, 0.f};

    // ---- prologue: stage tiles 0,1,2; tile 0 complete; prime frags(0) ----
    stage(0, 0);
    stage(1, 1);
    stage(2, 2);
    WAITVM(8);
    blockbar();

    bf16x8 af[4], bfA[4], bfB[4];
    #pragma unroll
    for (int mi = 0; mi < 4; ++mi)
        af[mi] = *(const bf16x8*)((uint8_t*)lds[0][0] + (slabA + mi) * 1024 + lo);
    #pragma unroll
    for (int ni = 0; ni < 4; ++ni)
        bfA[ni] = *(const bf16x8*)((uint8_t*)lds[0][1] + (slabB + ni) * 1024 + lo);

    // ---- main loop: 64 K-steps of 32, 1 barrier each ----
    auto kstep = [&](int t, bf16x8 (&bfc)[4], bf16x8 (&bfn)[4]) {
        uint8_t* bufT = (uint8_t*)lds[t & 3][0];

        // phase A: read ag(t) (slabs +4..+7), MFMA-A (acc rows 0..63)
        bf16x8 ag[4];
        #pragma unroll
        for (int mi = 0; mi < 4; ++mi)
            ag[mi] = *(const bf16x8*)(bufT + (slabA + 4 + mi) * 1024 + lo);
        __builtin_amdgcn_s_setprio(1);
        #pragma unroll
        for (int mi = 0; mi < 4; ++mi)
            #pragma unroll
            for (int ni = 0; ni < 4; ++ni)
                acc[mi][ni] = __builtin_amdgcn_mfma_f32_16x16x32_bf16(
                    af[mi], bfc[ni], acc[mi][ni], 0, 0, 0);
        __builtin_amdgcn_s_setprio(0);

        // mid: drain own ds_reads; tile t+1 DMA-complete; publish via barrier
        WAITLGKM0;
        if (t < 62) { WAITVM(4); } else { WAITVM(0); }
        blockbar();

        // phase B: issue DMA for tile t+3, read frags(t+1), MFMA-B
        if (t + 3 < 64) stage((t + 3) & 3, t + 3);
        if (t + 1 < 64) {
            uint8_t* bufNA = (uint8_t*)lds[(t + 1) & 3][0];
            uint8_t* bufNB = (uint8_t*)lds[(t + 1) & 3][1];
            #pragma unroll
            for (int ni = 0; ni < 4; ++ni)
                bfn[ni] = *(const bf16x8*)(bufNB + (slabB + ni) * 1024 + lo);
            #pragma unroll
            for (int mi = 0; mi < 4; ++mi)
                af[mi] = *(const bf16x8*)(bufNA + (slabA + mi) * 1024 + lo);
        }
        __builtin_amdgcn_s_setprio(1);
        #pragma unroll
        for (int mi = 0; mi < 4; ++mi)
            #pragma unroll
            for (int ni = 0; ni < 4; ++ni)
                acc[mi + 4][ni] = __builtin_amdgcn_mfma_f32_16x16x32_bf16(
                    ag[mi], bfc[ni], acc[mi + 4][ni], 0, 0, 0);
        __builtin_amdgcn_s_setprio(0);
    };

    #pragma unroll 1
    for (int t2 = 0; t2 < 32; ++t2) {
        kstep(2 * t2,     bfA, bfB);
        kstep(2 * t2 + 1, bfB, bfA);
    }

    // ---- epilogue: bias + relu, fp32 store ----
    // C/D layout (verified): col = lane&15, row = quad*4 + r
    const int rowBase = mT * 256 + wm + quad * 4;
    const int colBase = nT * 256 + wn + fr;
    #pragma unroll
    for (int mi = 0; mi < 8; ++mi) {
        #pragma unroll
        for (int ni = 0; ni < 4; ++ni) {
            const int col = colBase + ni * 16;
            #pragma unroll
            for (int r = 0; r < 4; ++r) {
                const int row = rowBase + mi * 16 + r;
                out[(size_t)row * kN + col] = fmaxf(acc[mi][ni][r] + bv[ni], 0.f);
            }
        }
    }
}

// ===================== fallback (R2 kernel, no-workspace path) ==============
#define TILE_M 128
#define TILE_N 128
#define TILE_K 32
#define LDS_STRIDE 20
__global__ __launch_bounds__(256)
void wsib_gemm_fb(const float* __restrict__ words, const float* __restrict__ sents,
                  const float* __restrict__ W, const float* __restrict__ bias,
                  const int* __restrict__ smap, float* __restrict__ out)
{
    __shared__ uint32_t Asm[TILE_M * LDS_STRIDE];
    __shared__ uint32_t Bsm[TILE_N * LDS_STRIDE];
    const int tid = threadIdx.x, nT = blockIdx.x, mT = blockIdx.y;
    const int sRow = tid >> 1, half = tid & 1;
    const int mRow = mT * TILE_M + sRow, bIdx = mRow >> 12;
    const float* wsrc = words + (size_t)mRow * kD + half * 16;
    const int sidx = smap[mRow];
    const float* ssrc = (sidx >= 0) ? sents + ((size_t)bIdx * kS + sidx) * kD + half * 16 : nullptr;
    const float* bsrc = W + (size_t)(nT * TILE_N + sRow) * kK + half * 16;
    uint32_t* adst = &Asm[sRow * LDS_STRIDE + half * 8];
    uint32_t* bdst = &Bsm[sRow * LDS_STRIDE + half * 8];
    const int lane = tid & 63, wv = tid >> 6;
    const int wm = (wv & 1) * 64, wn = (wv >> 1) * 64;
    const int fr = lane & 15, quad = lane >> 4;
    f32x4 acc[4][4];
    #pragma unroll
    for (int i = 0; i < 4; ++i)
        #pragma unroll
        for (int j = 0; j < 4; ++j) acc[i][j] = (f32x4){0.f, 0.f, 0.f, 0.f};
    float4 ra[4], rb[4];
    {
        const float4* pa = (const float4*)wsrc; const float4* pb = (const float4*)bsrc;
        #pragma unroll
        for (int i = 0; i < 4; ++i) { ra[i] = pa[i]; rb[i] = pb[i]; }
    }
    for (int k0 = 0; k0 < kK; k0 += TILE_K) {
        uint32_t pa[8], pb[8];
        #pragma unroll
        for (int i = 0; i < 4; ++i) {
            pa[2*i] = pk_bf16x2(ra[i].x, ra[i].y); pa[2*i+1] = pk_bf16x2(ra[i].z, ra[i].w);
            pb[2*i] = pk_bf16x2(rb[i].x, rb[i].y); pb[2*i+1] = pk_bf16x2(rb[i].z, rb[i].w);
        }
        __syncthreads();
        ((uint4*)adst)[0] = make_uint4(pa[0], pa[1], pa[2], pa[3]);
        ((uint4*)adst)[1] = make_uint4(pa[4], pa[5], pa[6], pa[7]);
        ((uint4*)bdst)[0] = make_uint4(pb[0], pb[1], pb[2], pb[3]);
        ((uint4*)bdst)[1] = make_uint4(pb[4], pb[5], pb[6], pb[7]);
        __syncthreads();
        const int k1 = k0 + TILE_K;
        if (k1 < kK) {
            const float* asrc = (k1 < kD) ? (wsrc + k1) : (ssrc ? (ssrc + (k1 - kD)) : nullptr);
            if (asrc) { const float4* p = (const float4*)asrc;
                #pragma unroll
                for (int i = 0; i < 4; ++i) ra[i] = p[i];
            } else {
                #pragma unroll
                for (int i = 0; i < 4; ++i) ra[i] = make_float4(0.f, 0.f, 0.f, 0.f);
            }
            const float4* p = (const float4*)(bsrc + k1);
            #pragma unroll
            for (int i = 0; i < 4; ++i) rb[i] = p[i];
        }
        bf16x8 af[4], bfv[4];
        #pragma unroll
        for (int mi = 0; mi < 4; ++mi)
            af[mi] = *(const bf16x8*)&Asm[(wm + mi * 16 + fr) * LDS_STRIDE + quad * 4];
        #pragma unroll
        for (int ni = 0; ni < 4; ++ni)
            bfv[ni] = *(const bf16x8*)&Bsm[(wn + ni * 16 + fr) * LDS_STRIDE + quad * 4];
        #pragma unroll
        for (int mi = 0; mi < 4; ++mi)
            #pragma unroll
            for (int ni = 0; ni < 4; ++ni)
                acc[mi][ni] = __builtin_amdgcn_mfma_f32_16x16x32_bf16(af[mi], bfv[ni], acc[mi][ni], 0, 0, 0);
    }
    const int rowBase = mT * TILE_M + wm, colBase = nT * TILE_N + wn;
    float bv[4];
    #pragma unroll
    for (int ni = 0; ni < 4; ++ni) bv[ni] = bias[colBase + ni * 16 + fr];
    #pragma unroll
    for (int mi = 0; mi < 4; ++mi)
        #pragma unroll
        for (int ni = 0; ni < 4; ++ni) {
            const int col = colBase + ni * 16 + fr;
            #pragma unroll
            for (int r = 0; r < 4; ++r) {
                const int row = rowBase + mi * 16 + quad * 4 + r;
                out[(size_t)row * kN + col] = fmaxf(acc[mi][ni][r] + bv[ni], 0.f);
            }
        }
}

extern "C" void kernel_launch(void* const* d_in, const int* in_sizes, int n_in,
                              void* d_out, int out_size, void* d_ws, size_t ws_size,
                              hipStream_t stream) {
    const float* words = (const float*)d_in[0];   // [8, 4096, 1024] f32
    const float* sents = (const float*)d_in[1];   // [8, 255, 1024]  f32
    const float* W     = (const float*)d_in[2];   // [1024, 2048]    f32
    const float* bias  = (const float*)d_in[3];   // [1024]          f32
    const int*   smap  = (const int*)d_in[4];     // [8, 4096]       i32
    float* out = (float*)d_out;                   // [8, 4096, 1024] f32

    if (ws_size >= WS_NEED) {
        uint8_t* ws = (uint8_t*)d_ws;
        uint4* wordsB = (uint4*)(ws + WS_WORDS);
        uint4* sentsB = (uint4*)(ws + WS_SENTS);
        uint4* WB     = (uint4*)(ws + WS_W);
        uint32_t* zp  = (uint32_t*)(ws + WS_ZP);
        cvt_prepass3<<<4096, 256, 0, stream>>>(
            (const float4*)words, (const float4*)sents, (const float4*)W,
            wordsB, sentsB, WB, zp);
        dim3 grid(kN / 256, kM / 256);            // (4, 128)
        wsib_gemm_v7<<<grid, 512, 0, stream>>>(
            (const uint8_t*)wordsB, (const uint8_t*)sentsB, (const uint8_t*)WB,
            bias, smap, (const uint8_t*)zp, out);
    } else {
        dim3 grid(kN / TILE_N, kM / TILE_M);
        wsib_gemm_fb<<<grid, 256, 0, stream>>>(words, sents, W, bias, smap, out);
    }
}